// Round 1
// 90.927 us; speedup vs baseline: 1.5401x; 1.5401x over previous
//
#include <hip/hip_runtime.h>

// Chamfer loss, B=8, N=M=8192, D=3, fp32 I/O — MFMA rewrite (R3).
//
// Scalar pass1 was VALU-issue-bound (VALUBusy ~112%, MfmaUtil 0): 3.58
// instr/pair at the 78.6e12 lane-instr/s issue ceiling + VALU clock
// throttle = 92.5us floor. Move the dot products to the matrix pipe:
//
//   v_mfma_f32_32x32x16_f16: D[32b x 32a] = sum_k A[b,k]*B[k,a]
//   K-slot layout (13 of 16 used), coords pre-scaled by 16 (exact):
//     k0-2 : bh_xyz * ah_xyz      (hi halves, f16)
//     k3-5 : bl_xyz * ah_xyz      (b lo-residual terms)
//     k6-8 : bh_xyz * al_xyz      (a lo-residual terms)
//     k9-10: (ch, cl) * (1, 1)    c = -0.5*|b|^2 split hi/lo
//     k11-12: (1, 1) * (dh, dl)   d = -0.5*|a|^2 split hi/lo
//   => v = ab - |a|^2/2 - |b|^2/2 = -d2/2 (scaled x256), error ~1e-4 abs.
//   min_b d2 = -2*max_b v; fold 16 acc regs with v_max3_f32 (8/mfma).
//   Rows (b-index) are max-reduced, so the A-row mapping is irrelevant;
//   K-permutations cancel (identical A/B fragment conventions).
//
// Block: 256 thr / 4 waves, one (batch,dir), 256 a-pts (2 tiles/wave in
// reg a-frags), streams a 4096-pt b-half via 32KB LDS in 4 chunks,
// pre-formatted to fragment order: main loop = ds_read_b128 + 2 mfma +
// 16 max3 per 2048 pairs. Grid 16*32*2 = 1024 (4 blk/CU, 4 waves/SIMD).

#define BATCH   8
#define NPTS    8192
#define BLK     256
#define TOTAL_A (2 * BATCH * NPTS)            // 131072
#define NCH2    2                             // b-halves per (batch,dir)
#define BHALF   (NPTS / NCH2)                 // 4096
#define CHUNK   1024                          // staged b-points per round
#define NCHUNK  (BHALF / CHUNK)               // 4
#define TILES   (CHUNK / 32)                  // 32
#define ABLKS   (NPTS / 256)                  // 32
#define P1_BLOCKS (2 * BATCH * ABLKS * NCH2)  // 1024
#define P2_BLOCKS (TOTAL_A / BLK)             // 512
#define SC      16.0f                         // exact pow2 coord scale

typedef _Float16 f16x8  __attribute__((ext_vector_type(8)));
typedef float    f32x16 __attribute__((ext_vector_type(16)));

static __device__ __forceinline__ unsigned int pk2(float a, float b) {
  unsigned short ua = __builtin_bit_cast(unsigned short, (_Float16)a);
  unsigned short ub = __builtin_bit_cast(unsigned short, (_Float16)b);
  return (unsigned int)ua | ((unsigned int)ub << 16);
}

// 16 accumulator values + running max -> 8 v_max3_f32
static __device__ __forceinline__ float fold16(float mq, f32x16 d) {
  float t0 = fmaxf(fmaxf(d[0],  d[1]),  d[2]);
  float t1 = fmaxf(fmaxf(d[3],  d[4]),  d[5]);
  float t2 = fmaxf(fmaxf(d[6],  d[7]),  d[8]);
  float t3 = fmaxf(fmaxf(d[9],  d[10]), d[11]);
  float t4 = fmaxf(fmaxf(d[12], d[13]), d[14]);
  float t5 = fmaxf(fmaxf(t0, t1), t2);
  float t6 = fmaxf(fmaxf(t3, t4), d[15]);
  return fmaxf(fmaxf(mq, t5), t6);
}

// format one b-point into the A-operand fragment layout in LDS.
// tile = p>>5 (32 pts each, 1KB): bytes [0,512) = k0-7 rows (lanes 0-31),
// [512,1024) = k8-15 rows (lanes 32-63); 16B per point per half.
static __device__ __forceinline__ void stage_point(char* lds, int p,
                                                   float X, float Y, float Z) {
  float x = X * SC, y = Y * SC, z = Z * SC;
  float fx = (float)(_Float16)x, fy = (float)(_Float16)y, fz = (float)(_Float16)z;
  float lx = x - fx, ly = y - fy, lz = z - fz;
  float b2 = fmaf(x, x, fmaf(y, y, z * z));
  float c  = -0.5f * b2;
  float fc = (float)(_Float16)c;
  float lc = c - fc;
  // k0-7:  bh_x bh_y | bh_z bl_x | bl_y bl_z | bh_x bh_y
  uint4 lo = make_uint4(pk2(x, y), pk2(z, lx), pk2(ly, lz), pk2(x, y));
  // k8-15: bh_z ch   | cl 1      | 1 0       | 0 0
  uint4 hi = make_uint4(pk2(z, c), pk2(lc, 1.0f), 0x00003C00u, 0u);
  int base = ((p >> 5) << 10) + ((p & 31) << 4);
  *(uint4*)(lds + base)       = lo;
  *(uint4*)(lds + base + 512) = hi;
}

// B-operand fragment for one a-point (col = lane&31, k-group = lane>>5)
static __device__ __forceinline__ f16x8 make_afrag(float X, float Y, float Z,
                                                   int hi) {
  float x = X * SC, y = Y * SC, z = Z * SC;
  float fx = (float)(_Float16)x, fy = (float)(_Float16)y, fz = (float)(_Float16)z;
  float lx = x - fx, ly = y - fy, lz = z - fz;
  float a2 = fmaf(x, x, fmaf(y, y, z * z));
  float dd = -0.5f * a2;
  float fd = (float)(_Float16)dd;
  float ld = dd - fd;
  uint4 u;
  if (!hi) {
    // k0-7:  ah_x ah_y | ah_z ah_x | ah_y ah_z | al_x al_y
    u = make_uint4(pk2(x, y), pk2(z, x), pk2(y, z), pk2(lx, ly));
  } else {
    // k8-15: al_z 1    | 1 dh      | dl 0      | 0 0
    u = make_uint4(pk2(lz, 1.0f), pk2(1.0f, dd), pk2(ld, 0.0f), 0u);
  }
  return __builtin_bit_cast(f16x8, u);
}

__global__ __launch_bounds__(BLK, 4) void chamfer_mfma_pass1(
    const float* __restrict__ pred, const float* __restrict__ gt,
    float* __restrict__ partial) {
  __shared__ uint4 lds4[CHUNK * 2];   // 32 KB fragment buffer
  char* lds = (char*)lds4;

  const int bid   = blockIdx.x;
  const int bhalf = bid & 1;
  const int r     = bid >> 1;
  const int ablk  = r & (ABLKS - 1);
  const int bd    = r >> 5;           // 0..15 = side*8 + batch
  const int batch = bd & 7;
  const int side  = bd >> 3;

  const float* A  = side ? gt : pred;
  const float* Bp = side ? pred : gt;

  const int t    = threadIdx.x;
  const int lane = t & 63;
  const int wave = t >> 6;
  const int col  = lane & 31;
  const int hi   = lane >> 5;

  // two 32-pt a-tiles per wave, fragments held in registers
  const int abase = ablk * 256 + wave * 64;
  const float* Ab = A + (size_t)batch * NPTS * 3;
  float x0 = Ab[(abase + col) * 3 + 0];
  float y0 = Ab[(abase + col) * 3 + 1];
  float z0 = Ab[(abase + col) * 3 + 2];
  float x1 = Ab[(abase + 32 + col) * 3 + 0];
  float y1 = Ab[(abase + 32 + col) * 3 + 1];
  float z1 = Ab[(abase + 32 + col) * 3 + 2];
  f16x8 af0 = make_afrag(x0, y0, z0, hi);
  f16x8 af1 = make_afrag(x1, y1, z1, hi);

  const float* Bbase = Bp + ((size_t)batch * NPTS + (size_t)bhalf * BHALF) * 3;

  float mq0 = -3.0e38f, mq1 = -3.0e38f;
  const f32x16 zero = {};
  const char* lread = lds + lane * 16;

  for (int c = 0; c < NCHUNK; ++c) {
    __syncthreads();
    // stage+format 1024 b-points; p = t + k*256 keeps ds_write_b128
    // lane-contiguous (conflict-free, 2-way at most)
#pragma unroll
    for (int k = 0; k < 4; ++k) {
      int p = t + k * 256;
      const float* q = Bbase + (size_t)(c * CHUNK + p) * 3;
      stage_point(lds, p, q[0], q[1], q[2]);
    }
    __syncthreads();

#pragma unroll
    for (int tile = 0; tile < TILES; ++tile) {
      f16x8 bf = *(const f16x8*)(lread + tile * 1024);
      f32x16 d0 = __builtin_amdgcn_mfma_f32_32x32x16_f16(bf, af0, zero, 0, 0, 0);
      f32x16 d1 = __builtin_amdgcn_mfma_f32_32x32x16_f16(bf, af1, zero, 0, 0, 0);
      mq0 = fold16(mq0, d0);
      mq1 = fold16(mq1, d1);
    }
  }

  // lanes l and l+32 hold the same a-col over disjoint b-rows
  mq0 = fmaxf(mq0, __shfl_xor(mq0, 32));
  mq1 = fmaxf(mq1, __shfl_xor(mq1, 32));

  if (lane < 32) {
    size_t a0 = (size_t)bd * NPTS + abase + col;
    partial[a0 * NCH2 + bhalf]        = mq0;
    partial[(a0 + 32) * NCH2 + bhalf] = mq1;
  }
}

__global__ __launch_bounds__(BLK) void chamfer_mfma_pass2(
    const float2* __restrict__ partial, float* __restrict__ blockSums) {
  const int gid = blockIdx.x * BLK + threadIdx.x;   // [0, TOTAL_A)
  float2 p = partial[gid];
  // v = -d2_scaled/2, scale = 256  =>  d2 = max(v0,v1) * (-1/128), clamp 0
  float d2 = fmaxf(fmaxf(p.x, p.y) * (-1.0f / 128.0f), 0.0f);

  float v = d2;
  for (int off = 32; off > 0; off >>= 1) v += __shfl_down(v, off);
  __shared__ float wsum[BLK / 64];
  int lane = threadIdx.x & 63, wv = threadIdx.x >> 6;
  if (lane == 0) wsum[wv] = v;
  __syncthreads();
  if (wv == 0) {
    float s = (lane < (BLK / 64)) ? wsum[lane] : 0.0f;
    for (int off = 2; off > 0; off >>= 1) s += __shfl_down(s, off);
    if (lane == 0) blockSums[blockIdx.x] = s;
  }
}

__global__ __launch_bounds__(BLK) void chamfer_pass3(
    const float* __restrict__ blockSums, float* __restrict__ out) {
  const int t = threadIdx.x;
  float v = blockSums[t] + blockSums[t + BLK];   // 512 sums
  for (int off = 32; off > 0; off >>= 1) v += __shfl_down(v, off);
  __shared__ float wsum[BLK / 64];
  int lane = t & 63, wv = t >> 6;
  if (lane == 0) wsum[wv] = v;
  __syncthreads();
  if (t == 0) {
    float s = wsum[0] + wsum[1] + wsum[2] + wsum[3];
    out[0] = s * (1.0f / (float)TOTAL_A);   // (sum1+sum2)/(2*65536)
  }
}

extern "C" void kernel_launch(void* const* d_in, const int* in_sizes, int n_in,
                              void* d_out, int out_size, void* d_ws, size_t ws_size,
                              hipStream_t stream) {
  const float* pred = (const float*)d_in[0];
  const float* gt   = (const float*)d_in[1];
  float* out = (float*)d_out;

  float* partial   = (float*)d_ws;                       // TOTAL_A*2 floats = 1 MB
  float* blockSums = partial + (size_t)TOTAL_A * NCH2;   // +512 floats

  chamfer_mfma_pass1<<<P1_BLOCKS, BLK, 0, stream>>>(pred, gt, partial);
  chamfer_mfma_pass2<<<P2_BLOCKS, BLK, 0, stream>>>((const float2*)partial, blockSums);
  chamfer_pass3<<<1, BLK, 0, stream>>>(blockSums, out);
}